// Round 7
// baseline (166.552 us; speedup 1.0000x reference)
//
#include <hip/hip_runtime.h>
#include <hip/hip_bf16.h>
#include <math.h>

#define BB 4
#define CC 64
#define DD 8
#define NN 4096
#define KS 8
#define KPS (NN / KS)          // 512 keys per split
#define LOG2E 1.44269504088896340736f

typedef __attribute__((ext_vector_type(4))) short short4v;      // 4 bf16
typedef __attribute__((ext_vector_type(8))) unsigned short ushort8;  // 16B
typedef __attribute__((ext_vector_type(16))) float f32x16;

// Device-pass-only builtins; host pass still semantic-checks __global__ bodies.
#if defined(__HIP_DEVICE_COMPILE__)
  #if __has_builtin(__builtin_amdgcn_mfma_f32_32x32x8bf16_1k)
    #define MFMA32x8(A, B, C) __builtin_amdgcn_mfma_f32_32x32x8bf16_1k(A, B, C, 0, 0, 0)
  #elif __has_builtin(__builtin_amdgcn_mfma_f32_32x32x8_bf16)
    #define MFMA32x8(A, B, C) __builtin_amdgcn_mfma_f32_32x32x8_bf16(A, B, C, 0, 0, 0)
  #else
    #error "no 32x32x8 bf16 MFMA builtin in device pass"
  #endif
#else
  static __device__ __host__ inline f32x16 MFMA32x8(short4v, short4v, f32x16 c) { return c; }
#endif

// ---------------------------------------------------------------------------
// Kernel 1: q/k/v projections -> bf16.  grid (B*16, 2):
//   z=0 -> v channels [0,32) + q (q pre-scaled by log2(e) so flash uses exp2)
//   z=1 -> v channels [32,64) + k
// q,k stored [B][N][8] bf16; v stored transposed [B][C][N] bf16.
// x read only 2x (8 MB total).
// ---------------------------------------------------------------------------
__global__ __launch_bounds__(256) void qkv_kernel(
    const float* __restrict__ x,  const float* __restrict__ Wq, const float* __restrict__ bq,
    const float* __restrict__ Wk, const float* __restrict__ bk,
    const float* __restrict__ Wv, const float* __restrict__ bv,
    __hip_bfloat16* __restrict__ qb, __hip_bfloat16* __restrict__ kb,
    unsigned short* __restrict__ vT)
{
#pragma clang fp contract(fast)
    int bx = blockIdx.x;             // B*16
    int z  = blockIdx.y;             // 0..1
    int b = bx >> 4;
    int n = (bx & 15) * 256 + threadIdx.x;

    const float* xb = x + (size_t)b * CC * NN + n;
    float xr[CC];
    #pragma unroll
    for (int c = 0; c < CC; ++c) xr[c] = xb[(size_t)c * NN];   // coalesced

    int e0 = z * 32;
    #pragma unroll
    for (int g = 0; g < 4; ++g) {
        float a[8];
        #pragma unroll
        for (int e = 0; e < 8; ++e) a[e] = bv[e0 + g * 8 + e];
        #pragma unroll
        for (int c = 0; c < CC; ++c) {
            float xc = xr[c];
            #pragma unroll
            for (int e = 0; e < 8; ++e)
                a[e] = fmaf(Wv[(e0 + g * 8 + e) * CC + c], xc, a[e]);
        }
        #pragma unroll
        for (int e = 0; e < 8; ++e) {
            __hip_bfloat16 h = __float2bfloat16(a[e]);
            vT[((size_t)b * CC + e0 + g * 8 + e) * NN + n] = *(unsigned short*)&h;
        }
    }

    {   // q (z=0) or k (z=1)
        bool isq = (z == 0);
        const float* W  = isq ? Wq : Wk;
        const float* bbp = isq ? bq : bk;
        __hip_bfloat16* o = isq ? qb : kb;
        float scale = isq ? LOG2E : 1.0f;
        __hip_bfloat16 t[DD];
        #pragma unroll
        for (int d = 0; d < DD; ++d) {
            float a = bbp[d];
            #pragma unroll
            for (int c = 0; c < CC; ++c)
                a = fmaf(W[d * CC + c], xr[c], a);
            t[d] = __float2bfloat16(a * scale);
        }
        *(uint4*)(o + ((size_t)b * NN + n) * DD) = *(uint4*)t;  // 16B coalesced
    }
}

// ---------------------------------------------------------------------------
// Kernel 2: MFMA flash partials. Fixes R6's 32-line V gathers by staging
// 128-key x 64-ch V tiles in LDS (coalesced global loads, 8 lines/instr),
// with 8-key-granule XOR swizzle (kg ^ (ch&3)) making the per-MFMA
// ds_read_b64 B-frags 2-way-conflict-free (2-way is free on gfx950).
// Global loads for tile t+1 are register-prefetched during tile t compute.
// S^T = mfma_32x32x8(A=K,B=Q) lands in the PV A-layout; exp2 in-register.
// Grid: BB * (N/128) * KS = 1024 blocks (4/CU, LDS 16.9KB each).
// ---------------------------------------------------------------------------
__global__ __launch_bounds__(256, 4) void flash_kernel(
    const __hip_bfloat16* __restrict__ qb, const __hip_bfloat16* __restrict__ kb,
    const unsigned short* __restrict__ vT, unsigned short* __restrict__ accb,
    float* __restrict__ sbuf)
{
    __shared__ unsigned short VS[64 * 132];   // [ch][132-key row], 264B stride
    int tid = threadIdx.x;
    int wave = tid >> 6, lane = tid & 63;
    int l32 = lane & 31, h2 = lane >> 5;

    int blk = blockIdx.x;            // ((qchunk*KS)+split)*4 + b  -> batch per XCD
    int b = blk & (BB - 1);
    int rest = blk >> 2;
    int split = rest & (KS - 1);
    int qchunk = rest >> 3;
    int n0 = qchunk * 128 + wave * 32;

    // Q B-frag: B[k=d=4h2+j][n=query=l32]
    short4v qf = *(const short4v*)(qb + ((size_t)b * NN + n0 + l32) * DD + h2 * 4);

    const __hip_bfloat16* kbb = kb + (size_t)b * NN * DD;
    const unsigned short* vbb = vT + (size_t)b * CC * NN;
    int m0 = split * KPS;

    // staging geometry: thread u-th slice: ch = u*16 + cch, granule kg (8 keys)
    int cch = tid >> 4, kg = tid & 15;
    int kgx = (kg ^ (cch & 3)) * 8;          // swizzled LDS granule offset (elems)

    f32x16 o0, o1, zz;
    #pragma unroll
    for (int r = 0; r < 16; ++r) { o0[r] = 0.f; o1[r] = 0.f; zz[r] = 0.f; }
    float ssum = 0.f;

    // preload tile 0
    ushort8 vr0 = *(const ushort8*)(vbb + (size_t)(cch)      * NN + m0 + kg * 8);
    ushort8 vr1 = *(const ushort8*)(vbb + (size_t)(16 + cch) * NN + m0 + kg * 8);
    ushort8 vr2 = *(const ushort8*)(vbb + (size_t)(32 + cch) * NN + m0 + kg * 8);
    ushort8 vr3 = *(const ushort8*)(vbb + (size_t)(48 + cch) * NN + m0 + kg * 8);

    for (int tile = 0; tile < 4; ++tile) {
        *(ushort8*)(VS + (size_t)(cch)      * 132 + kgx) = vr0;
        *(ushort8*)(VS + (size_t)(16 + cch) * 132 + kgx) = vr1;
        *(ushort8*)(VS + (size_t)(32 + cch) * 132 + kgx) = vr2;
        *(ushort8*)(VS + (size_t)(48 + cch) * 132 + kgx) = vr3;
        __syncthreads();

        if (tile < 3) {                       // prefetch next tile during compute
            int mn = m0 + (tile + 1) * 128;
            vr0 = *(const ushort8*)(vbb + (size_t)(cch)      * NN + mn + kg * 8);
            vr1 = *(const ushort8*)(vbb + (size_t)(16 + cch) * NN + mn + kg * 8);
            vr2 = *(const ushort8*)(vbb + (size_t)(32 + cch) * NN + mn + kg * 8);
            vr3 = *(const ushort8*)(vbb + (size_t)(48 + cch) * NN + mn + kg * 8);
        }

        // k frags for the 4 subiters of this tile (coalesced 8B loads)
        short4v kf[4];
        #pragma unroll
        for (int s = 0; s < 4; ++s)
            kf[s] = *(const short4v*)(kbb + (size_t)(m0 + tile * 128 + s * 32 + l32) * DD + h2 * 4);

        #pragma unroll
        for (int sub = 0; sub < 4; ++sub) {
            f32x16 st = MFMA32x8(kf[sub], qf, zz);
            float w[16];
            #pragma unroll
            for (int r = 0; r < 16; ++r) w[r] = exp2f(st[r]);
            ssum += (((w[0] + w[1]) + (w[2] + w[3])) + ((w[4] + w[5]) + (w[6] + w[7])))
                  + (((w[8] + w[9]) + (w[10] + w[11])) + ((w[12] + w[13]) + (w[14] + w[15])));

            union { short4v s; __hip_bfloat162 h[2]; } u[4];
            #pragma unroll
            for (int g = 0; g < 4; ++g) {
                u[g].h[0] = __float22bfloat162_rn(make_float2(w[4 * g],     w[4 * g + 1]));
                u[g].h[1] = __float22bfloat162_rn(make_float2(w[4 * g + 2], w[4 * g + 3]));
            }
            #pragma unroll
            for (int g = 0; g < 4; ++g) {
                int go = ((sub * 4 + g) ^ (l32 & 3)) * 8 + h2 * 4;   // swizzled read
                short4v vf0 = *(const short4v*)(VS + (size_t)(l32)      * 132 + go);
                short4v vf1 = *(const short4v*)(VS + (size_t)(32 + l32) * 132 + go);
                o0 = MFMA32x8(u[g].s, vf0, o0);
                o1 = MFMA32x8(u[g].s, vf1, o1);
            }
        }
        __syncthreads();
    }

    // O: D[row=query=(r&3)+8(r>>2)+4h2][col=channel]; bf16 accbuf (halved BW)
    __hip_bfloat16* ab = (__hip_bfloat16*)accb + (((size_t)(b * KS + split)) * NN + n0) * CC;
    #pragma unroll
    for (int r = 0; r < 16; ++r) {
        int qrow = (r & 3) + 8 * (r >> 2) + 4 * h2;
        ab[(size_t)qrow * CC + l32]      = __float2bfloat16(o0[r]);
        ab[(size_t)qrow * CC + 32 + l32] = __float2bfloat16(o1[r]);
    }
    ssum += __shfl_xor(ssum, 32);     // combine key-halves -> 32-key sums
    if (lane < 32)
        sbuf[(size_t)(b * KS + split) * NN + n0 + l32] = ssum;
}

// ---------------------------------------------------------------------------
// Kernel 3: reduce KS=8 splits (compile-time -> unrolled, pipelined loads),
// normalize, gamma*o + x.  Grid: B*256 blocks.
// ---------------------------------------------------------------------------
__global__ __launch_bounds__(256) void merge_kernel(
    const unsigned short* __restrict__ accb, const float* __restrict__ sbuf,
    const float* __restrict__ x, const float* __restrict__ gamma,
    float* __restrict__ out)
{
    __shared__ float tile[16 * 65];
    __shared__ float stl[16];
    int blk = blockIdx.x;            // B * 256
    int b = blk >> 8;
    int n0 = (blk & 255) * 16;
    int tid = threadIdx.x;

    if (tid < 16) {
        float st = 0.f;
        #pragma unroll
        for (int sp = 0; sp < KS; ++sp)
            st += sbuf[(size_t)(b * KS + sp) * NN + n0 + tid];
        stl[tid] = 1.0f / st;
    }
    const __hip_bfloat16* ac = (const __hip_bfloat16*)accb;
    #pragma unroll
    for (int p = 0; p < 4; ++p) {
        int e = p * 256 + tid;
        int c = e & 63, nl = e >> 6;
        float a = 0.f;
        #pragma unroll
        for (int sp = 0; sp < KS; ++sp)
            a += __bfloat162float(ac[(((size_t)(b * KS + sp) * NN) + n0 + nl) * CC + c]);
        tile[nl * 65 + c] = a;
    }
    __syncthreads();
    float g = gamma[0];
    #pragma unroll
    for (int p = 0; p < 4; ++p) {
        int e = p * 256 + tid;
        int nl = e & 15, c = e >> 4;
        size_t xi = ((size_t)b * CC + c) * NN + n0 + nl;
        out[xi] = g * tile[nl * 65 + c] * stl[nl] + x[xi];
    }
}

// ---------------------------------------------------------------------------
extern "C" void kernel_launch(void* const* d_in, const int* in_sizes, int n_in,
                              void* d_out, int out_size, void* d_ws, size_t ws_size,
                              hipStream_t stream)
{
    const float* x     = (const float*)d_in[0];
    const float* Wq    = (const float*)d_in[1];
    const float* bq    = (const float*)d_in[2];
    const float* Wk    = (const float*)d_in[3];
    const float* bk    = (const float*)d_in[4];
    const float* Wv    = (const float*)d_in[5];
    const float* bv    = (const float*)d_in[6];
    const float* gamma = (const float*)d_in[7];
    float* out = (float*)d_out;

    float* ws = (float*)d_ws;
    size_t off = 0;
    __hip_bfloat16* qb = (__hip_bfloat16*)(ws + off); off += (size_t)BB * NN * DD / 2 + 64;
    __hip_bfloat16* kb = (__hip_bfloat16*)(ws + off); off += (size_t)BB * NN * DD / 2 + 64;
    unsigned short* vT = (unsigned short*)(ws + off); off += (size_t)BB * CC * NN / 2 + 64;
    unsigned short* accb = (unsigned short*)(ws + off); off += (size_t)BB * KS * NN * CC / 2;  // bf16
    float* sbuf = ws + off; off += (size_t)BB * KS * NN;
    // total ~20 MB < ws_size (>=36 MB observed every round)

    qkv_kernel<<<dim3(BB * 16, 2), 256, 0, stream>>>(x, Wq, bq, Wk, bk, Wv, bv, qb, kb, vT);
    flash_kernel<<<BB * (NN / 128) * KS, 256, 0, stream>>>(qb, kb, vT, accb, sbuf);
    merge_kernel<<<BB * 256, 256, 0, stream>>>(accb, sbuf, x, gamma, out);
}

// Round 8
// 106.262 us; speedup vs baseline: 1.5674x; 1.5674x over previous
//
#include <hip/hip_runtime.h>
#include <hip/hip_bf16.h>
#include <math.h>

#define BB 4
#define CC 64
#define DD 8
#define NN 4096
#define KS 8
#define KPS (NN / KS)          // 512 keys per split
#define LOG2E 1.44269504088896340736f

typedef __attribute__((ext_vector_type(4))) short short4v;      // 4 bf16
typedef __attribute__((ext_vector_type(8))) unsigned short ushort8;  // 16B
typedef __attribute__((ext_vector_type(16))) float f32x16;

// Device-pass-only builtins; host pass still semantic-checks __global__ bodies.
#if defined(__HIP_DEVICE_COMPILE__)
  #if __has_builtin(__builtin_amdgcn_mfma_f32_32x32x8bf16_1k)
    #define MFMA32x8(A, B, C) __builtin_amdgcn_mfma_f32_32x32x8bf16_1k(A, B, C, 0, 0, 0)
  #elif __has_builtin(__builtin_amdgcn_mfma_f32_32x32x8_bf16)
    #define MFMA32x8(A, B, C) __builtin_amdgcn_mfma_f32_32x32x8_bf16(A, B, C, 0, 0, 0)
  #else
    #error "no 32x32x8 bf16 MFMA builtin in device pass"
  #endif
#else
  static __device__ __host__ inline f32x16 MFMA32x8(short4v, short4v, f32x16 c) { return c; }
#endif

static __device__ inline short4v pack4(float a, float b, float c, float d) {
    union { short4v s; __hip_bfloat162 h[2]; } u;
    u.h[0] = __float22bfloat162_rn(make_float2(a, b));
    u.h[1] = __float22bfloat162_rn(make_float2(c, d));
    return u.s;
}

// ---------------------------------------------------------------------------
// Kernel 1 (REWRITE): qkv as MFMA GEMM.  Y[96pad, N] = [Wv; Wq; Wk] @ x.
// R7's version stalled on s_load weight fetches (VALUBusy 15%, 65 us).
// Here W comes in as float4 VECTOR loads -> A-frags held in VGPRs; x streams
// as the B operand.  Per wave: one 32-row tile x 32 cols, 8 chained MFMAs.
// rt 0/1 (v rows) store straight to vT[B][C][N]; rt 2 (q rows 0-7, k rows
// 8-15, pad 16-31) transposes via 4KB LDS to the [B][N][8] layout flash uses.
// Grid: ((ng*3 + rt)*4 + b), ng in [0,32) -> 384 blocks, 4 waves = 128 n.
// ---------------------------------------------------------------------------
__global__ __launch_bounds__(256) void qkv_kernel(
    const float* __restrict__ x,  const float* __restrict__ Wq, const float* __restrict__ bq,
    const float* __restrict__ Wk, const float* __restrict__ bk,
    const float* __restrict__ Wv, const float* __restrict__ bv,
    unsigned short* __restrict__ qb, unsigned short* __restrict__ kb,
    unsigned short* __restrict__ vT)
{
    __shared__ unsigned short LQ[128 * 8];   // q transpose staging
    __shared__ unsigned short LK[128 * 8];   // k transpose staging

    int tid = threadIdx.x;
    int wave = tid >> 6, lane = tid & 63;
    int l32 = lane & 31, h2 = lane >> 5;

    int blk = blockIdx.x;
    int b = blk & (BB - 1);
    int r2 = blk >> 2;
    int rt = r2 % 3;                 // row-tile: 0,1 = v[0:32),[32:64); 2 = q/k
    int ng = r2 / 3;                 // n-group
    int n0 = ng * 128 + wave * 32;

    // ---- A-frags: W rows rt*32+l32, k = s*8 + 4*h2 + j  (vector float4 loads)
    short4v af[8];
    #pragma unroll
    for (int s = 0; s < 8; ++s) {
        float4 w4;
        if (rt < 2) {
            w4 = *(const float4*)(Wv + (size_t)(rt * 32 + l32) * CC + s * 8 + 4 * h2);
        } else if (l32 < 8) {
            w4 = *(const float4*)(Wq + (size_t)l32 * CC + s * 8 + 4 * h2);
        } else if (l32 < 16) {
            w4 = *(const float4*)(Wk + (size_t)(l32 - 8) * CC + s * 8 + 4 * h2);
        } else {
            w4 = make_float4(0.f, 0.f, 0.f, 0.f);
        }
        af[s] = pack4(w4.x, w4.y, w4.z, w4.w);
    }

    // ---- B-frags: x[b][c = s*8+4*h2+j][n0+l32]  (coalesced dword loads)
    const float* xb = x + (size_t)b * CC * NN + n0 + l32;
    short4v bf[8];
    #pragma unroll
    for (int s = 0; s < 8; ++s) {
        int c0 = s * 8 + 4 * h2;
        float x0 = xb[(size_t)(c0 + 0) * NN];
        float x1 = xb[(size_t)(c0 + 1) * NN];
        float x2 = xb[(size_t)(c0 + 2) * NN];
        float x3 = xb[(size_t)(c0 + 3) * NN];
        bf[s] = pack4(x0, x1, x2, x3);
    }

    f32x16 acc;
    #pragma unroll
    for (int r = 0; r < 16; ++r) acc[r] = 0.f;
    #pragma unroll
    for (int s = 0; s < 8; ++s)
        acc = MFMA32x8(af[s], bf[s], acc);

    if (rt < 2) {
        // v rows: D[row][n] + bias -> vT[b][row][n0+l32]
        #pragma unroll
        for (int r = 0; r < 16; ++r) {
            int row = rt * 32 + (r & 3) + 8 * (r >> 2) + 4 * h2;
            float val = acc[r] + bv[row];
            __hip_bfloat16 hv = __float2bfloat16(val);
            vT[((size_t)b * CC + row) * NN + n0 + l32] = *(unsigned short*)&hv;
        }
    } else {
        // q: regs 0-3 (rows 0-7), k: regs 4-7 (rows 8-15); transpose via LDS
        short4v qp = pack4((acc[0] + bq[0 + 4 * h2]) * LOG2E,
                           (acc[1] + bq[1 + 4 * h2]) * LOG2E,
                           (acc[2] + bq[2 + 4 * h2]) * LOG2E,
                           (acc[3] + bq[3 + 4 * h2]) * LOG2E);
        short4v kp = pack4(acc[4] + bk[0 + 4 * h2],
                           acc[5] + bk[1 + 4 * h2],
                           acc[6] + bk[2 + 4 * h2],
                           acc[7] + bk[3 + 4 * h2]);
        int nl = wave * 32 + l32;
        *(short4v*)(LQ + (size_t)nl * 8 + 4 * h2) = qp;
        *(short4v*)(LK + (size_t)nl * 8 + 4 * h2) = kp;
        __syncthreads();
        if (tid < 128) {
            ushort8 row = *(const ushort8*)(LQ + (size_t)tid * 8);
            *(ushort8*)(qb + ((size_t)b * NN + ng * 128 + tid) * 8) = row;
        } else {
            int t = tid - 128;
            ushort8 row = *(const ushort8*)(LK + (size_t)t * 8);
            *(ushort8*)(kb + ((size_t)b * NN + ng * 128 + t) * 8) = row;
        }
    }
}

// ---------------------------------------------------------------------------
// Kernel 2: MFMA flash partials (unchanged from R7). 128-key x 64-ch V tiles
// staged in LDS with 8-key-granule XOR swizzle; register prefetch of the next
// tile; S^T = mfma_32x32x8(A=K,B=Q) lands in the PV A-layout; exp2 in-reg.
// Grid: BB * (N/128) * KS = 1024 blocks.
// ---------------------------------------------------------------------------
__global__ __launch_bounds__(256, 4) void flash_kernel(
    const unsigned short* __restrict__ qb, const unsigned short* __restrict__ kb,
    const unsigned short* __restrict__ vT, unsigned short* __restrict__ accb,
    float* __restrict__ sbuf)
{
    __shared__ unsigned short VS[64 * 132];   // [ch][132-key row]
    int tid = threadIdx.x;
    int wave = tid >> 6, lane = tid & 63;
    int l32 = lane & 31, h2 = lane >> 5;

    int blk = blockIdx.x;            // ((qchunk*KS)+split)*4 + b  -> batch per XCD
    int b = blk & (BB - 1);
    int rest = blk >> 2;
    int split = rest & (KS - 1);
    int qchunk = rest >> 3;
    int n0 = qchunk * 128 + wave * 32;

    // Q B-frag: B[k=d=4h2+j][n=query=l32]
    short4v qf = *(const short4v*)(qb + ((size_t)b * NN + n0 + l32) * DD + h2 * 4);

    const unsigned short* kbb = kb + (size_t)b * NN * DD;
    const unsigned short* vbb = vT + (size_t)b * CC * NN;
    int m0 = split * KPS;

    int cch = tid >> 4, kg = tid & 15;
    int kgx = (kg ^ (cch & 3)) * 8;          // swizzled LDS granule offset

    f32x16 o0, o1, zz;
    #pragma unroll
    for (int r = 0; r < 16; ++r) { o0[r] = 0.f; o1[r] = 0.f; zz[r] = 0.f; }
    float ssum = 0.f;

    ushort8 vr0 = *(const ushort8*)(vbb + (size_t)(cch)      * NN + m0 + kg * 8);
    ushort8 vr1 = *(const ushort8*)(vbb + (size_t)(16 + cch) * NN + m0 + kg * 8);
    ushort8 vr2 = *(const ushort8*)(vbb + (size_t)(32 + cch) * NN + m0 + kg * 8);
    ushort8 vr3 = *(const ushort8*)(vbb + (size_t)(48 + cch) * NN + m0 + kg * 8);

    for (int tile = 0; tile < 4; ++tile) {
        *(ushort8*)(VS + (size_t)(cch)      * 132 + kgx) = vr0;
        *(ushort8*)(VS + (size_t)(16 + cch) * 132 + kgx) = vr1;
        *(ushort8*)(VS + (size_t)(32 + cch) * 132 + kgx) = vr2;
        *(ushort8*)(VS + (size_t)(48 + cch) * 132 + kgx) = vr3;
        __syncthreads();

        if (tile < 3) {
            int mn = m0 + (tile + 1) * 128;
            vr0 = *(const ushort8*)(vbb + (size_t)(cch)      * NN + mn + kg * 8);
            vr1 = *(const ushort8*)(vbb + (size_t)(16 + cch) * NN + mn + kg * 8);
            vr2 = *(const ushort8*)(vbb + (size_t)(32 + cch) * NN + mn + kg * 8);
            vr3 = *(const ushort8*)(vbb + (size_t)(48 + cch) * NN + mn + kg * 8);
        }

        short4v kf[4];
        #pragma unroll
        for (int s = 0; s < 4; ++s)
            kf[s] = *(const short4v*)(kbb + (size_t)(m0 + tile * 128 + s * 32 + l32) * DD + h2 * 4);

        #pragma unroll
        for (int sub = 0; sub < 4; ++sub) {
            f32x16 st = MFMA32x8(kf[sub], qf, zz);
            float w[16];
            #pragma unroll
            for (int r = 0; r < 16; ++r) w[r] = exp2f(st[r]);
            ssum += (((w[0] + w[1]) + (w[2] + w[3])) + ((w[4] + w[5]) + (w[6] + w[7])))
                  + (((w[8] + w[9]) + (w[10] + w[11])) + ((w[12] + w[13]) + (w[14] + w[15])));

            union { short4v s; __hip_bfloat162 h[2]; } u[4];
            #pragma unroll
            for (int g = 0; g < 4; ++g) {
                u[g].h[0] = __float22bfloat162_rn(make_float2(w[4 * g],     w[4 * g + 1]));
                u[g].h[1] = __float22bfloat162_rn(make_float2(w[4 * g + 2], w[4 * g + 3]));
            }
            #pragma unroll
            for (int g = 0; g < 4; ++g) {
                int go = ((sub * 4 + g) ^ (l32 & 3)) * 8 + h2 * 4;
                short4v vf0 = *(const short4v*)(VS + (size_t)(l32)      * 132 + go);
                short4v vf1 = *(const short4v*)(VS + (size_t)(32 + l32) * 132 + go);
                o0 = MFMA32x8(u[g].s, vf0, o0);
                o1 = MFMA32x8(u[g].s, vf1, o1);
            }
        }
        __syncthreads();
    }

    __hip_bfloat16* ab = (__hip_bfloat16*)accb + (((size_t)(b * KS + split)) * NN + n0) * CC;
    #pragma unroll
    for (int r = 0; r < 16; ++r) {
        int qrow = (r & 3) + 8 * (r >> 2) + 4 * h2;
        ab[(size_t)qrow * CC + l32]      = __float2bfloat16(o0[r]);
        ab[(size_t)qrow * CC + 32 + l32] = __float2bfloat16(o1[r]);
    }
    ssum += __shfl_xor(ssum, 32);
    if (lane < 32)
        sbuf[(size_t)(b * KS + split) * NN + n0 + l32] = ssum;
}

// ---------------------------------------------------------------------------
// Kernel 3: reduce KS=8 splits, normalize, gamma*o + x. Grid: B*256 blocks.
// ---------------------------------------------------------------------------
__global__ __launch_bounds__(256) void merge_kernel(
    const unsigned short* __restrict__ accb, const float* __restrict__ sbuf,
    const float* __restrict__ x, const float* __restrict__ gamma,
    float* __restrict__ out)
{
    __shared__ float tile[16 * 65];
    __shared__ float stl[16];
    int blk = blockIdx.x;            // B * 256
    int b = blk >> 8;
    int n0 = (blk & 255) * 16;
    int tid = threadIdx.x;

    if (tid < 16) {
        float st = 0.f;
        #pragma unroll
        for (int sp = 0; sp < KS; ++sp)
            st += sbuf[(size_t)(b * KS + sp) * NN + n0 + tid];
        stl[tid] = 1.0f / st;
    }
    const __hip_bfloat16* ac = (const __hip_bfloat16*)accb;
    #pragma unroll
    for (int p = 0; p < 4; ++p) {
        int e = p * 256 + tid;
        int c = e & 63, nl = e >> 6;
        float a = 0.f;
        #pragma unroll
        for (int sp = 0; sp < KS; ++sp)
            a += __bfloat162float(ac[(((size_t)(b * KS + sp) * NN) + n0 + nl) * CC + c]);
        tile[nl * 65 + c] = a;
    }
    __syncthreads();
    float g = gamma[0];
    #pragma unroll
    for (int p = 0; p < 4; ++p) {
        int e = p * 256 + tid;
        int nl = e & 15, c = e >> 4;
        size_t xi = ((size_t)b * CC + c) * NN + n0 + nl;
        out[xi] = g * tile[nl * 65 + c] * stl[nl] + x[xi];
    }
}

// ---------------------------------------------------------------------------
extern "C" void kernel_launch(void* const* d_in, const int* in_sizes, int n_in,
                              void* d_out, int out_size, void* d_ws, size_t ws_size,
                              hipStream_t stream)
{
    const float* x     = (const float*)d_in[0];
    const float* Wq    = (const float*)d_in[1];
    const float* bq    = (const float*)d_in[2];
    const float* Wk    = (const float*)d_in[3];
    const float* bk    = (const float*)d_in[4];
    const float* Wv    = (const float*)d_in[5];
    const float* bv    = (const float*)d_in[6];
    const float* gamma = (const float*)d_in[7];
    float* out = (float*)d_out;

    float* ws = (float*)d_ws;
    size_t off = 0;
    unsigned short* qb = (unsigned short*)(ws + off); off += (size_t)BB * NN * DD / 2 + 64;
    unsigned short* kb = (unsigned short*)(ws + off); off += (size_t)BB * NN * DD / 2 + 64;
    unsigned short* vT = (unsigned short*)(ws + off); off += (size_t)BB * CC * NN / 2 + 64;
    unsigned short* accb = (unsigned short*)(ws + off); off += (size_t)BB * KS * NN * CC / 2;
    float* sbuf = ws + off; off += (size_t)BB * KS * NN;

    qkv_kernel<<<BB * 3 * 32, 256, 0, stream>>>(x, Wq, bq, Wk, bk, Wv, bv, qb, kb, vT);
    flash_kernel<<<BB * (NN / 128) * KS, 256, 0, stream>>>(qb, kb, vT, accb, sbuf);
    merge_kernel<<<BB * 256, 256, 0, stream>>>(accb, sbuf, x, gamma, out);
}